// Round 1
// baseline (908.533 us; speedup 1.0000x reference)
//
#include <hip/hip_runtime.h>
#include <hip/hip_bf16.h>
#include <math.h>

#define KPRE 512
#define CAP 4096
#define MAXDET 300
#define SCORE_THR 0.05f
#define IOU_THR 0.5f
#define NREP 16            // LDS histogram replicas (hot-address dilution)
#define NSEL 32            // blocks per batch for parallel select passes

// Monotone 16-bit bin for valid keys: all keys in (bits(0.05), bits(1.0)] have
// (key>>10) in [0xF5334, 0xFE000] -> &0xFFFF strips the constant 0xF0000.
// Granularity = 1024 ulps; bin 0 is reserved for invalid (key==0).
__device__ __forceinline__ unsigned key_bin(unsigned key) {
    return (key >> 10) & 0xFFFFu;
}

// ---------------- Kernel A: pure streaming per-anchor max/argmax (NO atomics) ----------
// 4 consecutive lanes own one anchor; lane q reads float4s q, q+4, ... Composite
// (scorebits<<32)|(255-class) makes max == (score desc, class asc).
template<int F4A>
__global__ __launch_bounds__(256)
void score_label_kernel(const float* __restrict__ cls,
                        unsigned* __restrict__ keys,
                        unsigned char* __restrict__ labels,
                        int N) {
    const int b = blockIdx.y;
    const int tid = threadIdx.x;
    const int g = tid >> 2, q = tid & 3;
    const int a = blockIdx.x * 64 + g;
    if (a >= N) return;                       // 4-lane group uniform
    const float4* p = (const float4*)cls + ((size_t)b * N + a) * F4A;

    float4 vv[F4A / 4];
#pragma unroll
    for (int j = 0; j < F4A / 4; ++j) vv[j] = p[q + 4 * j];   // all loads in flight

    unsigned long long best = 0ull;
#pragma unroll
    for (int j = 0; j < F4A / 4; ++j) {
        float4 v = vv[j];
        int cbase = (q + 4 * j) * 4;
        float m = v.x; int c = cbase;
        if (v.y > m) { m = v.y; c = cbase + 1; }
        if (v.z > m) { m = v.z; c = cbase + 2; }
        if (v.w > m) { m = v.w; c = cbase + 3; }
        unsigned long long comp =
            ((unsigned long long)__float_as_uint(m) << 32) | (unsigned)(255 - c);
        if (comp > best) best = comp;
    }
    unsigned long long o;
    o = (unsigned long long)__shfl_xor((long long)best, 1, 64); if (o > best) best = o;
    o = (unsigned long long)__shfl_xor((long long)best, 2, 64); if (o > best) best = o;

    if (q == 0) {
        unsigned sb = (unsigned)(best >> 32);
        unsigned cl = 255u - (unsigned)(best & 0xFFFFFFFFull);
        size_t idx = (size_t)b * N + a;
        keys[idx] = (__uint_as_float(sb) > SCORE_THR) ? sb : 0u;
        labels[idx] = (unsigned char)cl;
    }
}

__global__ __launch_bounds__(256)
void score_label_generic(const float* __restrict__ cls,
                         unsigned* __restrict__ keys,
                         unsigned char* __restrict__ labels,
                         int N, int C) {
    const int b = blockIdx.y;
    const int tid = threadIdx.x;
    const int g = tid >> 2, q = tid & 3;
    const int a = blockIdx.x * 64 + g;
    if (a >= N) return;
    const int F4A = C >> 2;
    const float4* p = (const float4*)cls + ((size_t)b * N + a) * F4A;
    unsigned long long best = 0ull;
    for (int f4 = q; f4 < F4A; f4 += 4) {
        float4 v = p[f4];
        int cbase = f4 * 4;
        float m = v.x; int c = cbase;
        if (v.y > m) { m = v.y; c = cbase + 1; }
        if (v.z > m) { m = v.z; c = cbase + 2; }
        if (v.w > m) { m = v.w; c = cbase + 3; }
        unsigned long long comp =
            ((unsigned long long)__float_as_uint(m) << 32) | (unsigned)(255 - c);
        if (comp > best) best = comp;
    }
    unsigned long long o;
    o = (unsigned long long)__shfl_xor((long long)best, 1, 64); if (o > best) best = o;
    o = (unsigned long long)__shfl_xor((long long)best, 2, 64); if (o > best) best = o;
    if (q == 0) {
        unsigned sb = (unsigned)(best >> 32);
        unsigned cl = 255u - (unsigned)(best & 0xFFFFFFFFull);
        size_t idx = (size_t)b * N + a;
        keys[idx] = (__uint_as_float(sb) > SCORE_THR) ? sb : 0u;
        labels[idx] = (unsigned char)cl;
    }
}

// ---------------- init: zero the global hist/meta/counters ----------------
__global__ __launch_bounds__(256)
void init_kernel(unsigned* __restrict__ ghist1, unsigned* __restrict__ ghist2,
                 int* __restrict__ gmeta, unsigned* __restrict__ gH,
                 unsigned* __restrict__ gcnt, int B) {
    const int t = blockIdx.x * 256 + threadIdx.x;
    if (t < B * 256) { ghist1[t] = 0u; ghist2[t] = 0u; }
    if (t < B) { gmeta[2 * t] = -1; gmeta[2 * t + 1] = 0; gH[t] = 1u; gcnt[t] = 0u; }
}

// ---------------- pass 1 (parallel): coarse 256-bin histogram ----------------
__global__ __launch_bounds__(256)
void hist_coarse_kernel(const unsigned* __restrict__ keys,
                        unsigned* __restrict__ ghist1, int N) {
    const int b = blockIdx.y, tid = threadIdx.x;
    __shared__ unsigned h[NREP * 256];
    for (int i = tid; i < NREP * 256; i += 256) h[i] = 0u;
    __syncthreads();
    const unsigned rrep = (tid & (NREP - 1)) * 256;
    const unsigned* kb = keys + (size_t)b * N;
    const uint4* k4 = (const uint4*)kb;
    const int N4 = N >> 2;
    for (int i = blockIdx.x * 256 + tid; i < N4; i += 256 * NSEL) {
        uint4 v = k4[i];
        if (v.x) atomicAdd(&h[rrep + (key_bin(v.x) >> 8)], 1u);
        if (v.y) atomicAdd(&h[rrep + (key_bin(v.y) >> 8)], 1u);
        if (v.z) atomicAdd(&h[rrep + (key_bin(v.z) >> 8)], 1u);
        if (v.w) atomicAdd(&h[rrep + (key_bin(v.w) >> 8)], 1u);
    }
    if (blockIdx.x == 0) {
        for (int i = (N4 << 2) + tid; i < N; i += 256) {
            unsigned kk = kb[i];
            if (kk) atomicAdd(&h[rrep + (key_bin(kk) >> 8)], 1u);
        }
    }
    __syncthreads();
    unsigned s = 0;
    for (int j = 0; j < NREP; ++j) s += h[j * 256 + tid];
    if (s) atomicAdd(&ghist1[b * 256 + tid], s);
}

// ---------------- pick coarse threshold bin H1 per batch ----------------
__global__ __launch_bounds__(256)
void thresh1_kernel(const unsigned* __restrict__ ghist1, int* __restrict__ gmeta) {
    const int b = blockIdx.x, tid = threadIdx.x;
    __shared__ unsigned sscan[256];
    sscan[tid] = ghist1[b * 256 + tid];
    __syncthreads();
    for (int off = 1; off < 256; off <<= 1) {
        unsigned v = sscan[tid] + ((tid + off < 256) ? sscan[tid + off] : 0u);
        __syncthreads();
        sscan[tid] = v;
        __syncthreads();
    }
    unsigned above = (tid < 255) ? sscan[tid + 1] : 0u;
    if (sscan[tid] >= KPRE && above < KPRE) {
        gmeta[2 * b] = tid;
        gmeta[2 * b + 1] = (int)above;
    }
    // if total valid < KPRE: no tid qualifies -> gmeta stays {-1,0}, H stays 1
}

// ---------------- pass 2 (parallel): fine histogram within coarse bin H1 ----------------
__global__ __launch_bounds__(256)
void hist_fine_kernel(const unsigned* __restrict__ keys,
                      const int* __restrict__ gmeta,
                      unsigned* __restrict__ ghist2, int N) {
    const int b = blockIdx.y, tid = threadIdx.x;
    const int h1 = gmeta[2 * b];
    if (h1 < 0) return;                       // uniform: whole block exits
    __shared__ unsigned h[NREP * 256];
    for (int i = tid; i < NREP * 256; i += 256) h[i] = 0u;
    __syncthreads();
    const unsigned rrep = (tid & (NREP - 1)) * 256;
    const unsigned* kb = keys + (size_t)b * N;
    const uint4* k4 = (const uint4*)kb;
    const int N4 = N >> 2;
    for (int i = blockIdx.x * 256 + tid; i < N4; i += 256 * NSEL) {
        uint4 v = k4[i];
        unsigned fb;
        if (v.x) { fb = key_bin(v.x); if ((int)(fb >> 8) == h1) atomicAdd(&h[rrep + (fb & 255u)], 1u); }
        if (v.y) { fb = key_bin(v.y); if ((int)(fb >> 8) == h1) atomicAdd(&h[rrep + (fb & 255u)], 1u); }
        if (v.z) { fb = key_bin(v.z); if ((int)(fb >> 8) == h1) atomicAdd(&h[rrep + (fb & 255u)], 1u); }
        if (v.w) { fb = key_bin(v.w); if ((int)(fb >> 8) == h1) atomicAdd(&h[rrep + (fb & 255u)], 1u); }
    }
    if (blockIdx.x == 0) {
        for (int i = (N4 << 2) + tid; i < N; i += 256) {
            unsigned kk = kb[i];
            if (kk) { unsigned fb = key_bin(kk); if ((int)(fb >> 8) == h1) atomicAdd(&h[rrep + (fb & 255u)], 1u); }
        }
    }
    __syncthreads();
    unsigned s = 0;
    for (int j = 0; j < NREP; ++j) s += h[j * 256 + tid];
    if (s) atomicAdd(&ghist2[b * 256 + tid], s);
}

// ---------------- pick fine threshold H per batch ----------------
__global__ __launch_bounds__(256)
void thresh2_kernel(const unsigned* __restrict__ ghist2,
                    const int* __restrict__ gmeta, unsigned* __restrict__ gH) {
    const int b = blockIdx.x, tid = threadIdx.x;
    const int h1 = gmeta[2 * b];
    if (h1 < 0) return;                       // gH stays 1
    const unsigned above = (unsigned)gmeta[2 * b + 1];
    __shared__ unsigned sscan[256];
    sscan[tid] = ghist2[b * 256 + tid];
    __syncthreads();
    for (int off = 1; off < 256; off <<= 1) {
        unsigned v = sscan[tid] + ((tid + off < 256) ? sscan[tid + off] : 0u);
        __syncthreads();
        sscan[tid] = v;
        __syncthreads();
    }
    unsigned abv = ((tid < 255) ? sscan[tid + 1] : 0u) + above;
    if (sscan[tid] + above >= KPRE && abv < KPRE) {
        unsigned H = ((unsigned)h1 << 8) + (unsigned)tid;
        gH[b] = H ? H : 1u;
    }
}

// ---------------- collect (parallel): gather keys with fine bin >= H ----------------
__device__ __forceinline__ void emit_cand(unsigned key, unsigned idx, unsigned H,
                                          unsigned long long* __restrict__ cand,
                                          unsigned* __restrict__ cnt, int lane) {
    bool m = key_bin(key) >= H;
    unsigned long long mk = __ballot(m);
    if (!mk) return;
    int leader = __ffsll(mk) - 1;
    unsigned basep = 0;
    if (lane == leader) basep = atomicAdd(cnt, (unsigned)__popcll(mk));
    basep = (unsigned)__shfl((int)basep, leader, 64);
    if (m) {
        unsigned p = basep + (unsigned)__popcll(mk & ((1ull << lane) - 1ull));
        if (p < CAP) cand[p] = ((unsigned long long)key << 32) | ~idx;
    }
}

__global__ __launch_bounds__(256)
void collect_kernel(const unsigned* __restrict__ keys,
                    const unsigned* __restrict__ gH,
                    unsigned long long* __restrict__ gcand,
                    unsigned* __restrict__ gcnt, int N) {
    const int b = blockIdx.y, tid = threadIdx.x;
    const int lane = tid & 63;
    const unsigned H = gH[b];
    const unsigned* kb = keys + (size_t)b * N;
    const uint4* k4 = (const uint4*)kb;
    const int N4 = N >> 2;
    unsigned long long* cand = gcand + (size_t)b * CAP;
    unsigned* cnt = gcnt + b;
    for (int i = blockIdx.x * 256 + tid; i < N4; i += 256 * NSEL) {
        uint4 v = k4[i];
        unsigned base = (unsigned)(i << 2);
        emit_cand(v.x, base, H, cand, cnt, lane);
        emit_cand(v.y, base + 1u, H, cand, cnt, lane);
        emit_cand(v.z, base + 2u, H, cand, cnt, lane);
        emit_cand(v.w, base + 3u, H, cand, cnt, lane);
    }
    if (blockIdx.x == 0) {
        for (int i = (N4 << 2) + tid; i < N; i += 256)
            emit_cand(kb[i], (unsigned)i, H, cand, cnt, lane);
    }
}

// ---------------- final: sort + decode + NMS + output (one block per batch) ----------
__global__ __launch_bounds__(1024, 1)
void final_nms_kernel(const float* __restrict__ anchors,
                      const float* __restrict__ reg,
                      const float* __restrict__ sizes,
                      const unsigned char* __restrict__ labels,
                      const unsigned long long* __restrict__ gcand,
                      const unsigned* __restrict__ gcnt,
                      float* __restrict__ out,
                      int N, int B) {
    const int b = blockIdx.x;
    const int tid = threadIdx.x;
    const int nthr = blockDim.x;

    // buf (32KB) aliased: sort buffer during sort; sup[512*16] (32KB) in NMS
    __shared__ __align__(16) unsigned long long buf[CAP];
    unsigned* sup = (unsigned*)buf;
    __shared__ float4 boxs[KPRE];
    __shared__ float areas[KPRE];
    __shared__ unsigned ckey[KPRE];
    __shared__ unsigned cidx[KPRE];
    __shared__ unsigned validw[16], keepw_s[16], wpref[17];
    __shared__ int sh_M;

    int cnt = (int)gcnt[b];
    if (cnt > CAP) cnt = CAP;
    const unsigned long long* cand = gcand + (size_t)b * CAP;
    for (int i = tid; i < cnt; i += nthr) buf[i] = cand[i];
    if (tid == 0) {
        int M = KPRE;
        while (M < cnt) M <<= 1;
        sh_M = M;
    }
    __syncthreads();
    const int M = sh_M;
    for (int i2 = cnt + tid; i2 < M; i2 += nthr) buf[i2] = 0ull;
    __syncthreads();

    // ---- bitonic sort descending: key desc, index asc (composite uses ~idx) ----
    for (int kk = 2; kk <= M; kk <<= 1) {
        for (int j = kk >> 1; j > 0; j >>= 1) {
            for (int i2 = tid; i2 < M; i2 += nthr) {
                int l = i2 ^ j;
                if (l > i2) {
                    unsigned long long a = buf[i2], c = buf[l];
                    bool desc = ((i2 & kk) == 0);
                    if (desc ? (a < c) : (a > c)) { buf[i2] = c; buf[l] = a; }
                }
            }
            __syncthreads();
        }
    }

    // ---- extract top-512 candidates; decode + clip boxes (reference formula) ----
    const float wimg = sizes[b * 2 + 1];
    const float himg = sizes[b * 2 + 0];
    for (int t = tid; t < KPRE; t += nthr) {
        unsigned long long c = buf[t];
        unsigned key = (unsigned)(c >> 32);
        unsigned ai = ~(unsigned)(c & 0xFFFFFFFFull);
        bool valid = (key != 0u) && (t < cnt);
        ckey[t] = valid ? key : 0u;
        cidx[t] = valid ? ai : 0u;
        float4 bx = make_float4(0.f, 0.f, 0.f, 0.f);
        if (valid) {
            const float4 a4 = *(const float4*)(anchors + ((size_t)b * N + ai) * 4);
            const float4 r4 = *(const float4*)(reg + ((size_t)b * N + ai) * 4);
            float w = a4.z - a4.x, h = a4.w - a4.y;
            float cx = a4.x + 0.5f * w, cy = a4.y + 0.5f * h;
            float dx = r4.x * 0.1f, dy = r4.y * 0.1f;
            float dw = r4.z * 0.2f, dh = r4.w * 0.2f;
            float pcx = cx + dx * w, pcy = cy + dy * h;
            float pw = expf(dw) * w, ph = expf(dh) * h;
            float x1 = pcx - 0.5f * pw, y1 = pcy - 0.5f * ph;
            float x2 = pcx + 0.5f * pw, y2 = pcy + 0.5f * ph;
            bx.x = fminf(fmaxf(x1, 0.f), wimg);
            bx.y = fminf(fmaxf(y1, 0.f), himg);
            bx.z = fminf(fmaxf(x2, 0.f), wimg);
            bx.w = fminf(fmaxf(y2, 0.f), himg);
        }
        boxs[t] = bx;
        areas[t] = (bx.z - bx.x) * (bx.w - bx.y);
    }
    __syncthreads();

    // ---- suppression bitmatrix: sup[i][w] bit b = (iou(i, w*32+b) > 0.5) && (j > i) ----
    for (int unit = tid; unit < KPRE * 16; unit += nthr) {
        int i = unit >> 4, w = unit & 15;
        float4 bi = boxs[i];
        float ai = areas[i];
        unsigned bits = 0;
        int j0 = w * 32;
        for (int bit = 0; bit < 32; ++bit) {
            int j = j0 + bit;
            if (j > i) {
                float4 bj = boxs[j];
                float ltx = fmaxf(bi.x, bj.x), lty = fmaxf(bi.y, bj.y);
                float rbx = fminf(bi.z, bj.z), rby = fminf(bi.w, bj.w);
                float iw = fmaxf(rbx - ltx, 0.f), ih = fmaxf(rby - lty, 0.f);
                float inter = iw * ih;
                float iou = inter / (ai + areas[j] - inter + 1e-9f);
                if (iou > IOU_THR) bits |= (1u << bit);
            }
        }
        sup[i * 16 + w] = bits;
    }
    __syncthreads();

    // ---- validity bitmask via per-wave ballot ----
    unsigned long long bal = __ballot(tid < KPRE && ckey[tid] != 0u);
    if (tid < KPRE && (tid & 63) == 0) {
        validw[(tid >> 6) * 2] = (unsigned)(bal & 0xFFFFFFFFull);
        validw[(tid >> 6) * 2 + 1] = (unsigned)(bal >> 32);
    }
    __syncthreads();

    // ---- single-wave greedy NMS scan: lane w holds keep-word w in a register ----
    if (tid < 64) {
        unsigned kw = (tid < 16) ? validw[tid] : 0u;
        for (int i = 0; i < KPRE; ++i) {
            unsigned rw = sup[i * 16 + (tid & 15)];
            unsigned ow = __shfl(kw, i >> 5, 64);
            if ((ow >> (i & 31)) & 1u) kw &= ~rw;
        }
        if (tid < 16) keepw_s[tid] = kw;
    }
    __syncthreads();

    // ---- rank kept candidates (order = candidate order = score desc) ----
    if (tid == 0) {
        unsigned s = 0;
        for (int w2 = 0; w2 < 16; ++w2) { wpref[w2] = s; s += __popc(keepw_s[w2]); }
        wpref[16] = s;
    }
    __syncthreads();
    const unsigned nk = wpref[16];

    float* ob = out;                                   // [B,300,4]
    float* os = out + (size_t)B * MAXDET * 4;          // [B,300,1]
    float* ol = os + (size_t)B * MAXDET;               // [B,300,1]
    const unsigned char* lb = labels + (size_t)b * N;

    for (int t = tid; t < KPRE; t += nthr) {
        unsigned word = keepw_s[t >> 5];
        if ((word >> (t & 31)) & 1u) {
            unsigned rank = wpref[t >> 5] + __popc(word & ((1u << (t & 31)) - 1u));
            if (rank < MAXDET) {
                float4 bx = boxs[t];
                size_t ro = (size_t)b * MAXDET + rank;
                ob[ro * 4 + 0] = bx.x;
                ob[ro * 4 + 1] = bx.y;
                ob[ro * 4 + 2] = bx.z;
                ob[ro * 4 + 3] = bx.w;
                os[ro] = __uint_as_float(ckey[t]);
                ol[ro] = (float)lb[cidx[t]];
            }
        }
    }
    for (int r = tid; r < MAXDET; r += nthr) {
        if (r >= (int)nk) {
            size_t ro = (size_t)b * MAXDET + r;
            ob[ro * 4 + 0] = -1.f;
            ob[ro * 4 + 1] = -1.f;
            ob[ro * 4 + 2] = -1.f;
            ob[ro * 4 + 3] = -1.f;
            os[ro] = -1.f;
            ol[ro] = -1.f;
        }
    }
}

extern "C" void kernel_launch(void* const* d_in, const int* in_sizes, int n_in,
                              void* d_out, int out_size, void* d_ws, size_t ws_size,
                              hipStream_t stream) {
    const float* anchors = (const float*)d_in[0];
    const float* reg     = (const float*)d_in[1];
    const float* cls     = (const float*)d_in[2];
    const float* sizes   = (const float*)d_in[3];

    const int B = in_sizes[3] / 2;                    // 8
    const int N = in_sizes[0] / (4 * B);              // 200000
    const int C = in_sizes[2] / (B * N);              // 80
    const int total = B * N;

    // ws layout: keys [total u32] | labels [total u8] | ghist1 | ghist2 | gmeta | gH | gcnt | gcand
    char* ws = (char*)d_ws;
    size_t off = 0;
    unsigned* keys = (unsigned*)(ws + off);            off += (size_t)total * 4;
    unsigned char* labels = (unsigned char*)(ws + off); off += (size_t)total;
    off = (off + 255) & ~(size_t)255;
    unsigned* ghist1 = (unsigned*)(ws + off);          off += (size_t)B * 256 * 4;
    unsigned* ghist2 = (unsigned*)(ws + off);          off += (size_t)B * 256 * 4;
    int* gmeta = (int*)(ws + off);                     off += (size_t)B * 2 * 4;
    unsigned* gH = (unsigned*)(ws + off);              off += (size_t)B * 4;
    unsigned* gcnt = (unsigned*)(ws + off);            off += (size_t)B * 4;
    off = (off + 255) & ~(size_t)255;
    unsigned long long* gcand = (unsigned long long*)(ws + off);

    float* out = (float*)d_out;

    dim3 blkA(256);
    dim3 grdA((N + 63) / 64, B);
    if (C == 80)
        score_label_kernel<20><<<grdA, blkA, 0, stream>>>(cls, keys, labels, N);
    else
        score_label_generic<<<grdA, blkA, 0, stream>>>(cls, keys, labels, N, C);

    init_kernel<<<dim3((B * 256 + 255) / 256), dim3(256), 0, stream>>>(ghist1, ghist2, gmeta, gH, gcnt, B);
    hist_coarse_kernel<<<dim3(NSEL, B), dim3(256), 0, stream>>>(keys, ghist1, N);
    thresh1_kernel<<<dim3(B), dim3(256), 0, stream>>>(ghist1, gmeta);
    hist_fine_kernel<<<dim3(NSEL, B), dim3(256), 0, stream>>>(keys, gmeta, ghist2, N);
    thresh2_kernel<<<dim3(B), dim3(256), 0, stream>>>(ghist2, gmeta, gH);
    collect_kernel<<<dim3(NSEL, B), dim3(256), 0, stream>>>(keys, gH, gcand, gcnt, N);
    final_nms_kernel<<<dim3(B), dim3(1024), 0, stream>>>(anchors, reg, sizes, labels, gcand, gcnt, out, N, B);
}

// Round 2
// 907.764 us; speedup vs baseline: 1.0008x; 1.0008x over previous
//
#include <hip/hip_runtime.h>
#include <hip/hip_bf16.h>
#include <math.h>

#define KPRE 512
#define CAP 4096
#define MAXDET 300
#define SCORE_THR 0.05f
#define IOU_THR 0.5f
#define NREP 16            // LDS histogram replicas in fine pass (hot-address dilution)
#define NGR 4              // global coarse-hist replicas per batch (hot-bin dilution)
#define NSEL 32            // blocks per batch for parallel select passes

// Monotone 16-bit bin for valid keys: all keys in (bits(0.05), bits(1.0)] have
// (key>>10) in [0xF5334, 0xFE000] -> &0xFFFF strips the constant 0xF0000.
// Granularity = 1024 ulps; bin 0 is reserved for invalid (key==0).
__device__ __forceinline__ unsigned key_bin(unsigned key) {
    return (key >> 10) & 0xFFFFu;
}

// ---------------- init: zero the global hists + counters ----------------
__global__ __launch_bounds__(256)
void init_kernel(unsigned* __restrict__ ghist1, unsigned* __restrict__ ghist2,
                 unsigned* __restrict__ gcnt, int B) {
    const int t = blockIdx.x * 256 + threadIdx.x;
    if (t < B * NGR * 256) ghist1[t] = 0u;
    if (t < B * 256) ghist2[t] = 0u;
    if (t < B) gcnt[t] = 0u;
}

// ---------------- Kernel A: streaming per-anchor max/argmax + fused coarse hist ------
// 4 consecutive lanes own one anchor; lane q reads float4s q, q+4, ... Composite
// (scorebits<<32)|(255-class) makes max == (score desc, class asc).
template<int F4A>
__global__ __launch_bounds__(256)
void score_label_kernel(const float* __restrict__ cls,
                        unsigned* __restrict__ keys,
                        unsigned char* __restrict__ labels,
                        unsigned* __restrict__ ghist1,
                        int N) {
    const int b = blockIdx.y;
    const int tid = threadIdx.x;
    const int g = tid >> 2, q = tid & 3;
    const int a = blockIdx.x * 64 + g;

    __shared__ unsigned lh[4 * 256];
    for (int i = tid; i < 4 * 256; i += 256) lh[i] = 0u;
    __syncthreads();

    const bool active = (a < N);
    if (active) {
        const float4* p = (const float4*)cls + ((size_t)b * N + a) * F4A;

        float4 vv[F4A / 4];
#pragma unroll
        for (int j = 0; j < F4A / 4; ++j) vv[j] = p[q + 4 * j];   // all loads in flight

        unsigned long long best = 0ull;
#pragma unroll
        for (int j = 0; j < F4A / 4; ++j) {
            float4 v = vv[j];
            int cbase = (q + 4 * j) * 4;
            float m = v.x; int c = cbase;
            if (v.y > m) { m = v.y; c = cbase + 1; }
            if (v.z > m) { m = v.z; c = cbase + 2; }
            if (v.w > m) { m = v.w; c = cbase + 3; }
            unsigned long long comp =
                ((unsigned long long)__float_as_uint(m) << 32) | (unsigned)(255 - c);
            if (comp > best) best = comp;
        }
        unsigned long long o;
        o = (unsigned long long)__shfl_xor((long long)best, 1, 64); if (o > best) best = o;
        o = (unsigned long long)__shfl_xor((long long)best, 2, 64); if (o > best) best = o;

        if (q == 0) {
            unsigned sb = (unsigned)(best >> 32);
            unsigned cl = 255u - (unsigned)(best & 0xFFFFFFFFull);
            size_t idx = (size_t)b * N + a;
            unsigned keyv = (__uint_as_float(sb) > SCORE_THR) ? sb : 0u;
            keys[idx] = keyv;
            labels[idx] = (unsigned char)cl;
            if (keyv) atomicAdd(&lh[(g & 3) * 256 + (key_bin(keyv) >> 8)], 1u);
        }
    }
    __syncthreads();
    // merge 4 LDS replicas; one global atomic per nonzero bin, NGR-replicated per batch
    unsigned s = lh[tid] + lh[256 + tid] + lh[512 + tid] + lh[768 + tid];
    if (s) atomicAdd(&ghist1[((size_t)b * NGR + (blockIdx.x & (NGR - 1))) * 256 + tid], s);
}

__global__ __launch_bounds__(256)
void score_label_generic(const float* __restrict__ cls,
                         unsigned* __restrict__ keys,
                         unsigned char* __restrict__ labels,
                         unsigned* __restrict__ ghist1,
                         int N, int C) {
    const int b = blockIdx.y;
    const int tid = threadIdx.x;
    const int g = tid >> 2, q = tid & 3;
    const int a = blockIdx.x * 64 + g;

    __shared__ unsigned lh[4 * 256];
    for (int i = tid; i < 4 * 256; i += 256) lh[i] = 0u;
    __syncthreads();

    const bool active = (a < N);
    if (active) {
        const int F4A = C >> 2;
        const float4* p = (const float4*)cls + ((size_t)b * N + a) * F4A;
        unsigned long long best = 0ull;
        for (int f4 = q; f4 < F4A; f4 += 4) {
            float4 v = p[f4];
            int cbase = f4 * 4;
            float m = v.x; int c = cbase;
            if (v.y > m) { m = v.y; c = cbase + 1; }
            if (v.z > m) { m = v.z; c = cbase + 2; }
            if (v.w > m) { m = v.w; c = cbase + 3; }
            unsigned long long comp =
                ((unsigned long long)__float_as_uint(m) << 32) | (unsigned)(255 - c);
            if (comp > best) best = comp;
        }
        unsigned long long o;
        o = (unsigned long long)__shfl_xor((long long)best, 1, 64); if (o > best) best = o;
        o = (unsigned long long)__shfl_xor((long long)best, 2, 64); if (o > best) best = o;
        if (q == 0) {
            unsigned sb = (unsigned)(best >> 32);
            unsigned cl = 255u - (unsigned)(best & 0xFFFFFFFFull);
            size_t idx = (size_t)b * N + a;
            unsigned keyv = (__uint_as_float(sb) > SCORE_THR) ? sb : 0u;
            keys[idx] = keyv;
            labels[idx] = (unsigned char)cl;
            if (keyv) atomicAdd(&lh[(g & 3) * 256 + (key_bin(keyv) >> 8)], 1u);
        }
    }
    __syncthreads();
    unsigned s = lh[tid] + lh[256 + tid] + lh[512 + tid] + lh[768 + tid];
    if (s) atomicAdd(&ghist1[((size_t)b * NGR + (blockIdx.x & (NGR - 1))) * 256 + tid], s);
}

// ---------------- fine hist within coarse bin H1 (thresh1 recomputed per block) ------
__global__ __launch_bounds__(256)
void hist_fine_kernel(const unsigned* __restrict__ keys,
                      const unsigned* __restrict__ ghist1,
                      unsigned* __restrict__ ghist2, int N) {
    const int b = blockIdx.y, tid = threadIdx.x;
    __shared__ unsigned sscan[256];
    __shared__ int sh_h1;
    __shared__ unsigned lh[NREP * 256];
    if (tid == 0) sh_h1 = -1;
    const unsigned* g1 = ghist1 + (size_t)b * NGR * 256;
    sscan[tid] = g1[tid] + g1[256 + tid] + g1[512 + tid] + g1[768 + tid];
    __syncthreads();
    for (int off = 1; off < 256; off <<= 1) {
        unsigned v = sscan[tid] + ((tid + off < 256) ? sscan[tid + off] : 0u);
        __syncthreads();
        sscan[tid] = v;
        __syncthreads();
    }
    {
        unsigned above = (tid < 255) ? sscan[tid + 1] : 0u;
        if (sscan[tid] >= KPRE && above < KPRE) sh_h1 = tid;
    }
    __syncthreads();
    const int h1 = sh_h1;
    if (h1 < 0) return;                        // fewer than KPRE valid -> H = 1 downstream

    for (int i = tid; i < NREP * 256; i += 256) lh[i] = 0u;
    __syncthreads();
    const unsigned rrep = (tid & (NREP - 1)) * 256;
    const unsigned* kb = keys + (size_t)b * N;
    const uint4* k4 = (const uint4*)kb;
    const int N4 = N >> 2;
    for (int i = blockIdx.x * 256 + tid; i < N4; i += 256 * NSEL) {
        uint4 v = k4[i];
        unsigned fb;
        if (v.x) { fb = key_bin(v.x); if ((int)(fb >> 8) == h1) atomicAdd(&lh[rrep + (fb & 255u)], 1u); }
        if (v.y) { fb = key_bin(v.y); if ((int)(fb >> 8) == h1) atomicAdd(&lh[rrep + (fb & 255u)], 1u); }
        if (v.z) { fb = key_bin(v.z); if ((int)(fb >> 8) == h1) atomicAdd(&lh[rrep + (fb & 255u)], 1u); }
        if (v.w) { fb = key_bin(v.w); if ((int)(fb >> 8) == h1) atomicAdd(&lh[rrep + (fb & 255u)], 1u); }
    }
    if (blockIdx.x == 0) {
        for (int i = (N4 << 2) + tid; i < N; i += 256) {
            unsigned kk = kb[i];
            if (kk) { unsigned fb = key_bin(kk); if ((int)(fb >> 8) == h1) atomicAdd(&lh[rrep + (fb & 255u)], 1u); }
        }
    }
    __syncthreads();
    unsigned s = 0;
    for (int j = 0; j < NREP; ++j) s += lh[j * 256 + tid];
    if (s) atomicAdd(&ghist2[b * 256 + tid], s);
}

// ---------------- collect (thresh1+thresh2 recomputed per block) ----------------
__device__ __forceinline__ void emit_cand(unsigned key, unsigned idx, unsigned H,
                                          unsigned long long* __restrict__ cand,
                                          unsigned* __restrict__ cnt, int lane) {
    bool m = key_bin(key) >= H;
    unsigned long long mk = __ballot(m);
    if (!mk) return;
    int leader = __ffsll(mk) - 1;
    unsigned basep = 0;
    if (lane == leader) basep = atomicAdd(cnt, (unsigned)__popcll(mk));
    basep = (unsigned)__shfl((int)basep, leader, 64);
    if (m) {
        unsigned p = basep + (unsigned)__popcll(mk & ((1ull << lane) - 1ull));
        if (p < CAP) cand[p] = ((unsigned long long)key << 32) | ~idx;
    }
}

__global__ __launch_bounds__(256)
void collect_kernel(const unsigned* __restrict__ keys,
                    const unsigned* __restrict__ ghist1,
                    const unsigned* __restrict__ ghist2,
                    unsigned long long* __restrict__ gcand,
                    unsigned* __restrict__ gcnt, int N) {
    const int b = blockIdx.y, tid = threadIdx.x;
    __shared__ unsigned sscan[256];
    __shared__ int sh_h1;
    __shared__ unsigned sh_above, sh_H;
    if (tid == 0) { sh_h1 = -1; sh_H = 1u; }
    // --- recompute coarse threshold ---
    const unsigned* g1 = ghist1 + (size_t)b * NGR * 256;
    sscan[tid] = g1[tid] + g1[256 + tid] + g1[512 + tid] + g1[768 + tid];
    __syncthreads();
    for (int off = 1; off < 256; off <<= 1) {
        unsigned v = sscan[tid] + ((tid + off < 256) ? sscan[tid + off] : 0u);
        __syncthreads();
        sscan[tid] = v;
        __syncthreads();
    }
    {
        unsigned above = (tid < 255) ? sscan[tid + 1] : 0u;
        if (sscan[tid] >= KPRE && above < KPRE) { sh_h1 = tid; sh_above = above; }
    }
    __syncthreads();
    const int h1 = sh_h1;
    unsigned H = 1u;
    if (h1 >= 0) {
        // --- recompute fine threshold ---
        sscan[tid] = ghist2[b * 256 + tid];
        __syncthreads();
        for (int off = 1; off < 256; off <<= 1) {
            unsigned v = sscan[tid] + ((tid + off < 256) ? sscan[tid + off] : 0u);
            __syncthreads();
            sscan[tid] = v;
            __syncthreads();
        }
        unsigned abv = ((tid < 255) ? sscan[tid + 1] : 0u) + sh_above;
        if (sscan[tid] + sh_above >= KPRE && abv < KPRE) {
            unsigned Hc = ((unsigned)h1 << 8) + (unsigned)tid;
            sh_H = Hc ? Hc : 1u;
        }
        __syncthreads();
        H = sh_H;
    }

    const int lane = tid & 63;
    const unsigned* kb = keys + (size_t)b * N;
    const uint4* k4 = (const uint4*)kb;
    const int N4 = N >> 2;
    unsigned long long* cand = gcand + (size_t)b * CAP;
    unsigned* cnt = gcnt + b;
    for (int i = blockIdx.x * 256 + tid; i < N4; i += 256 * NSEL) {
        uint4 v = k4[i];
        unsigned base = (unsigned)(i << 2);
        emit_cand(v.x, base, H, cand, cnt, lane);
        emit_cand(v.y, base + 1u, H, cand, cnt, lane);
        emit_cand(v.z, base + 2u, H, cand, cnt, lane);
        emit_cand(v.w, base + 3u, H, cand, cnt, lane);
    }
    if (blockIdx.x == 0) {
        for (int i = (N4 << 2) + tid; i < N; i += 256)
            emit_cand(kb[i], (unsigned)i, H, cand, cnt, lane);
    }
}

// ---------------- final: sort + decode + NMS + output (one block per batch) ----------
__global__ __launch_bounds__(1024, 1)
void final_nms_kernel(const float* __restrict__ anchors,
                      const float* __restrict__ reg,
                      const float* __restrict__ sizes,
                      const unsigned char* __restrict__ labels,
                      const unsigned long long* __restrict__ gcand,
                      const unsigned* __restrict__ gcnt,
                      float* __restrict__ out,
                      int N, int B) {
    const int b = blockIdx.x;
    const int tid = threadIdx.x;
    const int nthr = blockDim.x;

    // buf (32KB) aliased: sort buffer during sort; sup[512*16] (32KB) in NMS
    __shared__ __align__(16) unsigned long long buf[CAP];
    unsigned* sup = (unsigned*)buf;
    __shared__ float4 boxs[KPRE];
    __shared__ float areas[KPRE];
    __shared__ unsigned ckey[KPRE];
    __shared__ unsigned cidx[KPRE];
    __shared__ unsigned validw[16], keepw_s[16], wpref[17];
    __shared__ int sh_M;

    int cnt = (int)gcnt[b];
    if (cnt > CAP) cnt = CAP;
    const unsigned long long* cand = gcand + (size_t)b * CAP;
    for (int i = tid; i < cnt; i += nthr) buf[i] = cand[i];
    if (tid == 0) {
        int M = KPRE;
        while (M < cnt) M <<= 1;
        sh_M = M;
    }
    __syncthreads();
    const int M = sh_M;
    for (int i2 = cnt + tid; i2 < M; i2 += nthr) buf[i2] = 0ull;
    __syncthreads();

    // ---- bitonic sort descending: key desc, index asc (composite uses ~idx) ----
    for (int kk = 2; kk <= M; kk <<= 1) {
        for (int j = kk >> 1; j > 0; j >>= 1) {
            for (int i2 = tid; i2 < M; i2 += nthr) {
                int l = i2 ^ j;
                if (l > i2) {
                    unsigned long long a = buf[i2], c = buf[l];
                    bool desc = ((i2 & kk) == 0);
                    if (desc ? (a < c) : (a > c)) { buf[i2] = c; buf[l] = a; }
                }
            }
            __syncthreads();
        }
    }

    // ---- extract top-512 candidates; decode + clip boxes (reference formula) ----
    const float wimg = sizes[b * 2 + 1];
    const float himg = sizes[b * 2 + 0];
    for (int t = tid; t < KPRE; t += nthr) {
        unsigned long long c = buf[t];
        unsigned key = (unsigned)(c >> 32);
        unsigned ai = ~(unsigned)(c & 0xFFFFFFFFull);
        bool valid = (key != 0u) && (t < cnt);
        ckey[t] = valid ? key : 0u;
        cidx[t] = valid ? ai : 0u;
        float4 bx = make_float4(0.f, 0.f, 0.f, 0.f);
        if (valid) {
            const float4 a4 = *(const float4*)(anchors + ((size_t)b * N + ai) * 4);
            const float4 r4 = *(const float4*)(reg + ((size_t)b * N + ai) * 4);
            float w = a4.z - a4.x, h = a4.w - a4.y;
            float cx = a4.x + 0.5f * w, cy = a4.y + 0.5f * h;
            float dx = r4.x * 0.1f, dy = r4.y * 0.1f;
            float dw = r4.z * 0.2f, dh = r4.w * 0.2f;
            float pcx = cx + dx * w, pcy = cy + dy * h;
            float pw = expf(dw) * w, ph = expf(dh) * h;
            float x1 = pcx - 0.5f * pw, y1 = pcy - 0.5f * ph;
            float x2 = pcx + 0.5f * pw, y2 = pcy + 0.5f * ph;
            bx.x = fminf(fmaxf(x1, 0.f), wimg);
            bx.y = fminf(fmaxf(y1, 0.f), himg);
            bx.z = fminf(fmaxf(x2, 0.f), wimg);
            bx.w = fminf(fmaxf(y2, 0.f), himg);
        }
        boxs[t] = bx;
        areas[t] = (bx.z - bx.x) * (bx.w - bx.y);
    }
    __syncthreads();

    // ---- suppression bitmatrix (upper triangle only):
    //      sup[i][w] bit b = (iou(i, w*32+b) > 0.5) && (j > i) ----
    for (int unit = tid; unit < KPRE * 16; unit += nthr) {
        int i = unit >> 4, w = unit & 15;
        int j0 = w * 32;
        int bstart = i - j0 + 1;
        if (bstart < 0) bstart = 0;
        unsigned bits = 0;
        if (bstart < 32) {
            float4 bi = boxs[i];
            float ai = areas[i];
            for (int bit = bstart; bit < 32; ++bit) {
                int j = j0 + bit;
                float4 bj = boxs[j];
                float ltx = fmaxf(bi.x, bj.x), lty = fmaxf(bi.y, bj.y);
                float rbx = fminf(bi.z, bj.z), rby = fminf(bi.w, bj.w);
                float iw = fmaxf(rbx - ltx, 0.f), ih = fmaxf(rby - lty, 0.f);
                float inter = iw * ih;
                float iou = inter / (ai + areas[j] - inter + 1e-9f);
                if (iou > IOU_THR) bits |= (1u << bit);
            }
        }
        sup[i * 16 + w] = bits;
    }
    __syncthreads();

    // ---- validity bitmask via per-wave ballot ----
    unsigned long long bal = __ballot(tid < KPRE && ckey[tid] != 0u);
    if (tid < KPRE && (tid & 63) == 0) {
        validw[(tid >> 6) * 2] = (unsigned)(bal & 0xFFFFFFFFull);
        validw[(tid >> 6) * 2 + 1] = (unsigned)(bal >> 32);
    }
    __syncthreads();

    // ---- single-wave greedy NMS scan: lane w holds keep-word w in a register ----
    if (tid < 64) {
        unsigned kw = (tid < 16) ? validw[tid] : 0u;
        for (int i = 0; i < KPRE; ++i) {
            unsigned rw = sup[i * 16 + (tid & 15)];
            unsigned ow = __shfl(kw, i >> 5, 64);
            if ((ow >> (i & 31)) & 1u) kw &= ~rw;
        }
        if (tid < 16) keepw_s[tid] = kw;
    }
    __syncthreads();

    // ---- rank kept candidates (order = candidate order = score desc) ----
    if (tid == 0) {
        unsigned s = 0;
        for (int w2 = 0; w2 < 16; ++w2) { wpref[w2] = s; s += __popc(keepw_s[w2]); }
        wpref[16] = s;
    }
    __syncthreads();
    const unsigned nk = wpref[16];

    float* ob = out;                                   // [B,300,4]
    float* os = out + (size_t)B * MAXDET * 4;          // [B,300,1]
    float* ol = os + (size_t)B * MAXDET;               // [B,300,1]
    const unsigned char* lb = labels + (size_t)b * N;

    for (int t = tid; t < KPRE; t += nthr) {
        unsigned word = keepw_s[t >> 5];
        if ((word >> (t & 31)) & 1u) {
            unsigned rank = wpref[t >> 5] + __popc(word & ((1u << (t & 31)) - 1u));
            if (rank < MAXDET) {
                float4 bx = boxs[t];
                size_t ro = (size_t)b * MAXDET + rank;
                ob[ro * 4 + 0] = bx.x;
                ob[ro * 4 + 1] = bx.y;
                ob[ro * 4 + 2] = bx.z;
                ob[ro * 4 + 3] = bx.w;
                os[ro] = __uint_as_float(ckey[t]);
                ol[ro] = (float)lb[cidx[t]];
            }
        }
    }
    for (int r = tid; r < MAXDET; r += nthr) {
        if (r >= (int)nk) {
            size_t ro = (size_t)b * MAXDET + r;
            ob[ro * 4 + 0] = -1.f;
            ob[ro * 4 + 1] = -1.f;
            ob[ro * 4 + 2] = -1.f;
            ob[ro * 4 + 3] = -1.f;
            os[ro] = -1.f;
            ol[ro] = -1.f;
        }
    }
}

extern "C" void kernel_launch(void* const* d_in, const int* in_sizes, int n_in,
                              void* d_out, int out_size, void* d_ws, size_t ws_size,
                              hipStream_t stream) {
    const float* anchors = (const float*)d_in[0];
    const float* reg     = (const float*)d_in[1];
    const float* cls     = (const float*)d_in[2];
    const float* sizes   = (const float*)d_in[3];

    const int B = in_sizes[3] / 2;                    // 8
    const int N = in_sizes[0] / (4 * B);              // 200000
    const int C = in_sizes[2] / (B * N);              // 80
    const int total = B * N;

    // ws layout: keys | labels | ghist1 (NGR replicas) | ghist2 | gcnt | gcand
    char* ws = (char*)d_ws;
    size_t off = 0;
    unsigned* keys = (unsigned*)(ws + off);            off += (size_t)total * 4;
    unsigned char* labels = (unsigned char*)(ws + off); off += (size_t)total;
    off = (off + 255) & ~(size_t)255;
    unsigned* ghist1 = (unsigned*)(ws + off);          off += (size_t)B * NGR * 256 * 4;
    unsigned* ghist2 = (unsigned*)(ws + off);          off += (size_t)B * 256 * 4;
    unsigned* gcnt = (unsigned*)(ws + off);            off += (size_t)B * 4;
    off = (off + 255) & ~(size_t)255;
    unsigned long long* gcand = (unsigned long long*)(ws + off);

    float* out = (float*)d_out;

    init_kernel<<<dim3((B * NGR * 256 + 255) / 256), dim3(256), 0, stream>>>(ghist1, ghist2, gcnt, B);

    dim3 blkA(256);
    dim3 grdA((N + 63) / 64, B);
    if (C == 80)
        score_label_kernel<20><<<grdA, blkA, 0, stream>>>(cls, keys, labels, ghist1, N);
    else
        score_label_generic<<<grdA, blkA, 0, stream>>>(cls, keys, labels, ghist1, N, C);

    hist_fine_kernel<<<dim3(NSEL, B), dim3(256), 0, stream>>>(keys, ghist1, ghist2, N);
    collect_kernel<<<dim3(NSEL, B), dim3(256), 0, stream>>>(keys, ghist1, ghist2, gcand, gcnt, N);
    final_nms_kernel<<<dim3(B), dim3(1024), 0, stream>>>(anchors, reg, sizes, labels, gcand, gcnt, out, N, B);
}